// Round 3
// baseline (10.249 us; speedup 1.0000x reference)
//
#include <hip/hip_runtime.h>
#include <math.h>

// QuanvolutionHybrid — analytic collapse of the 4-qubit circuit.
// RZ = diagonal phase, CX = basis permutation, initial state real product
// => params drop out. Final bits (a,b,c^a,d^b) give per-patch features:
//   e0=cos(x0), e1=cos(x1), e2=cos(x0)cos(x2), e3=cos(x1)cos(x3)
// logits = feats @ W^T + b; out = log_softmax(logits).
//
// v3: single exposed memory latency per wave —
//   global_load_lds(W) -> x loads -> cos features (pre-barrier) -> barrier ->
//   LDS-broadcast FMA loop -> DPP reduce -> softmax in lanes 31/63.

#define BSZ 4096

// v += value-from-DPP-shuffled-v ; invalid-source lanes add 0 (bound_ctrl).
#define DPP_ADD(v, ctrl, rmask)                                              \
    v += __int_as_float(__builtin_amdgcn_update_dpp(                         \
        0, __float_as_int(v), (ctrl), (rmask), 0xf, true))

__device__ __forceinline__ void load_lds16(const void* g, void* l) {
    __builtin_amdgcn_global_load_lds(
        (const __attribute__((address_space(1))) void*)g,
        (__attribute__((address_space(3))) void*)l, 16, 0, 0);
}

__global__ __launch_bounds__(256) void quanv_fused_v3(
    const float* __restrict__ x,     // [4096, 784]
    const float* __restrict__ W,     // [10, 784]
    const float* __restrict__ bias,  // [10]
    float* __restrict__ out)         // [4096, 10]
{
    __shared__ float sW[10 * 784];   // 31,360 B

    const int tid = threadIdx.x;

    // (1) W staging: direct global->LDS, issued before anything else.
    {
        const float4* Wv = (const float4*)W;
        float4* sWv = (float4*)sW;
        #pragma unroll
        for (int i = 0; i < 8; ++i) {
            const int idx = tid + i * 256;
            if (idx < 1960) load_lds16(Wv + idx, sWv + idx);
        }
    }

    const int wave = tid >> 6;           // 0..3
    const int lane = tid & 63;
    const int h    = lane >> 5;          // row within the pair
    const int kl   = lane & 31;          // patch-lane in the 32-group
    const int row  = blockIdx.x * 8 + wave * 2 + h;   // < 4096

    const float* __restrict__ xr = x + row * 784;

    // (2) All x loads in flight behind the W loads (one exposed latency).
    float2 a01[7], a23[7];
    #pragma unroll
    for (int t = 0; t < 7; ++t) {
        const int k = t * 32 + kl;
        const int kk = (t < 6 || kl < 4) ? k : 0;     // clamp inactive lanes
        const int r = kk / 14;
        const int c = kk - r * 14;
        const int base = r * 56 + c * 2;              // even -> 8B aligned
        a01[t] = *(const float2*)(xr + base);
        a23[t] = *(const float2*)(xr + base + 28);
    }

    // (3) Cos features BEFORE the barrier — hides the W-stage drain.
    float f[7][4];
    #pragma unroll
    for (int t = 0; t < 7; ++t) {
        f[t][0] = __cosf(a01[t].x);
        f[t][1] = __cosf(a01[t].y);
        f[t][2] = f[t][0] * __cosf(a23[t].x);
        f[t][3] = f[t][1] * __cosf(a23[t].y);
    }

    __syncthreads();   // W resident; all loads already drained by cos deps

    // (4) LDS FMA loop. Both 32-lane halves read identical addresses ->
    // 2-way same-address broadcast (free, m136).
    float acc[10];
    #pragma unroll
    for (int o = 0; o < 10; ++o) acc[o] = 0.f;

    #pragma unroll
    for (int t = 0; t < 7; ++t) {
        const int k = t * 32 + kl;
        if (t < 6 || kl < 4) {
            const float* wk = sW + k * 4;
            #pragma unroll
            for (int o = 0; o < 10; ++o) {
                const float4 w4 = *(const float4*)(wk + o * 784);
                acc[o] = fmaf(f[t][0], w4.x, acc[o]);
                acc[o] = fmaf(f[t][1], w4.y, acc[o]);
                acc[o] = fmaf(f[t][2], w4.z, acc[o]);
                acc[o] = fmaf(f[t][3], w4.w, acc[o]);
            }
        }
    }

    // (5) 32-lane DPP reduction per half; totals land in lanes 31 and 63.
    #pragma unroll
    for (int o = 0; o < 10; ++o) {
        float v = acc[o];
        DPP_ADD(v, 0x111, 0xf);   // row_shr:1
        DPP_ADD(v, 0x112, 0xf);   // row_shr:2
        DPP_ADD(v, 0x114, 0xf);   // row_shr:4
        DPP_ADD(v, 0x118, 0xf);   // row_shr:8
        DPP_ADD(v, 0x142, 0xa);   // row_bcast15 into rows 1,3
        acc[o] = v;
    }

    // (6) Finalize in the two total-holding lanes (31, 63).
    if (kl == 31) {
        float lg[10];
        float m = -1e30f;
        #pragma unroll
        for (int o = 0; o < 10; ++o) {
            lg[o] = acc[o] + bias[o];
            m = fmaxf(m, lg[o]);
        }
        float s = 0.f;
        #pragma unroll
        for (int o = 0; o < 10; ++o) s += __expf(lg[o] - m);
        const float lse = __logf(s) + m;
        float* orow = out + row * 10;
        #pragma unroll
        for (int o = 0; o < 10; ++o) orow[o] = lg[o] - lse;
    }
}

extern "C" void kernel_launch(void* const* d_in, const int* in_sizes, int n_in,
                              void* d_out, int out_size, void* d_ws, size_t ws_size,
                              hipStream_t stream) {
    const float* x    = (const float*)d_in[0];
    // d_in[1] = params — provably irrelevant (phases/permutations only).
    const float* W    = (const float*)d_in[2];
    const float* bias = (const float*)d_in[3];
    float* out = (float*)d_out;

    dim3 grid(BSZ / 8);   // 512 blocks: 4 waves/block, 2 rows/wave
    dim3 block(256);
    quanv_fused_v3<<<grid, block, 0, stream>>>(x, W, bias, out);
}